// Round 1
// baseline (222.510 us; speedup 1.0000x reference)
//
#include <hip/hip_runtime.h>
#include <math.h>

// GaussianSpot: out[1,B,F,D,D] = bg[b,f] + sum_k h/(2*pi*w^2) * exp(-((i-sx)^2+(j-sy)^2)/(2w^2))
// Separable: per (k,b,f) compute ex[i] (with coef folded) and ey[j], then pixel = bg + sum_k ex[i]*ey[j].
// Write-BW bound: 205.5 MB out -> ~33 us floor at 6.3 TB/s.

#define DD 14
#define BB 512
#define FFRAMES 512
#define NF_TAB 1024
#define PAIRS_PER_BLOCK 64
#define BLOCK 256

__global__ __launch_bounds__(BLOCK) void gauss_spot_kernel(
    const float* __restrict__ height, const float* __restrict__ width,
    const float* __restrict__ xoff, const float* __restrict__ yoff,
    const float* __restrict__ background, const float* __restrict__ target_locs,
    const int* __restrict__ n_idx, const int* __restrict__ f_tab,
    float* __restrict__ out)
{
    // lds[pair][sel][i]: sel = k*2 + isY. isY=0 -> x-row (i axis, coef folded), isY=1 -> y-row (j axis).
    __shared__ float lds[PAIRS_PER_BLOCK][4][DD];
    __shared__ float bg_s[PAIRS_PER_BLOCK];

    const int tid = threadIdx.x;
    const int pair_local = tid >> 2;      // 0..63
    const int sel = tid & 3;              // k*2 + isY
    const int k = sel >> 1;
    const int isY = sel & 1;
    const int pair = blockIdx.x * PAIRS_PER_BLOCK + pair_local;  // b*F + fi
    const int b = pair >> 9;              // F = 512
    const int fi = pair & (FFRAMES - 1);

    // ---- phase 1: 1 task per thread, 14 exps each ----
    const int n = n_idx[b];               // n_idx is [B,1]
    const int ff = f_tab[fi];
    const float loc = target_locs[(n * NF_TAB + ff) * 2 + isY]; // ch0 -> i (sx), ch1 -> j (sy)
    const int idx = k * (BB * FFRAMES) + pair;
    const float w = width[idx];
    const float off = isY ? yoff[idx] : xoff[idx];
    const float s = loc + off;
    const float inv2w2 = 1.0f / (2.0f * w * w);
    // coef = h / (2*pi*w^2) = h * inv2w2 * (1/pi); fold into x-row only
    const float coef = isY ? 1.0f : height[idx] * inv2w2 * 0.31830988618379067f;
    const float a = inv2w2 * 1.4426950408889634f;  // log2(e)/(2w^2)

    #pragma unroll
    for (int i = 0; i < DD; ++i) {
        float d = (float)i - s;
        lds[pair_local][sel][i] = coef * exp2f(-d * d * a);
    }
    if (sel == 0) bg_s[pair_local] = background[pair];
    __syncthreads();

    // ---- phase 2: coalesced float4 stores over block's contiguous 64*196-float region ----
    float4* outv = (float4*)(out + (size_t)blockIdx.x * (PAIRS_PER_BLOCK * DD * DD));
    const int NV = PAIRS_PER_BLOCK * DD * DD / 4;   // 3136
    for (int v = tid; v < NV; v += BLOCK) {
        int p = v / 49;                   // 196/4 = 49 float4 per AOI; never crosses AOI
        int pix0 = (v - p * 49) * 4;
        float bg = bg_s[p];
        float4 r;
        #pragma unroll
        for (int e = 0; e < 4; ++e) {
            int pix = pix0 + e;
            int i = pix / DD;
            int j = pix - i * DD;
            ((float*)&r)[e] = bg
                + lds[p][0][i] * lds[p][1][j]
                + lds[p][2][i] * lds[p][3][j];
        }
        outv[v] = r;
    }
}

extern "C" void kernel_launch(void* const* d_in, const int* in_sizes, int n_in,
                              void* d_out, int out_size, void* d_ws, size_t ws_size,
                              hipStream_t stream) {
    const float* height      = (const float*)d_in[0];
    const float* width       = (const float*)d_in[1];
    const float* x           = (const float*)d_in[2];
    const float* y           = (const float*)d_in[3];
    const float* background  = (const float*)d_in[4];
    const float* target_locs = (const float*)d_in[5];
    const int*   n_idx       = (const int*)d_in[6];
    const int*   f           = (const int*)d_in[7];
    float* out = (float*)d_out;

    const int total_pairs = BB * FFRAMES;              // 262144
    const int grid = total_pairs / PAIRS_PER_BLOCK;    // 4096
    gauss_spot_kernel<<<grid, BLOCK, 0, stream>>>(
        height, width, x, y, background, target_locs, n_idx, f, out);
}